// Round 1
// baseline (233.518 us; speedup 1.0000x reference)
//
#include <hip/hip_runtime.h>
#include <hip/hip_bf16.h>

// Problem constants (from reference)
#define NXv 128
#define NYv 128
#define NZv 8
#define NVOX (NXv * NYv * NZv)   // 131072
#define NV 6
#define NC 64
#define HFv 116
#define WFv 200
#define PLANE (HFv * WFv)        // 23200
// PAD_W/WF == PAD_H/HF == 8 exactly
#define INV8 0.125f

// ---------------------------------------------------------------------------
// Transpose [V][C][PLANE] -> [V][PLANE][C]  (channels-last for coalesced gather)
// 64 (c) x 64 (p) LDS tile, 256 threads.
// ---------------------------------------------------------------------------
__global__ __launch_bounds__(256) void transpose_feat(
    const float* __restrict__ in, float* __restrict__ out) {
  __shared__ float tile[64][65];
  const int v  = blockIdx.y;
  const int p0 = blockIdx.x * 64;
  const float* src = in  + (size_t)v * NC * PLANE;
  float*       dst = out + (size_t)v * PLANE * NC;
  const int t = threadIdx.x;

#pragma unroll
  for (int i = 0; i < 16; ++i) {
    int l = i * 256 + t;
    int c = l >> 6;        // 0..63
    int p = l & 63;
    int pp = p0 + p;
    tile[c][p] = (pp < PLANE) ? src[c * PLANE + pp] : 0.0f;  // coalesced read
  }
  __syncthreads();
#pragma unroll
  for (int i = 0; i < 16; ++i) {
    int l = i * 256 + t;
    int p = l >> 6;
    int c = l & 63;
    int pp = p0 + p;
    if (pp < PLANE) dst[(size_t)pp * NC + c] = tile[c][p];   // coalesced write
  }
}

// ---------------------------------------------------------------------------
// Main kernel: one wave per point, lane = channel.
// CHANNELS_LAST=true : feat is [V][PLANE][C] (transposed workspace)
// CHANNELS_LAST=false: feat is [V][C][PLANE] (original x_fov, fallback)
// ---------------------------------------------------------------------------
template <bool CHANNELS_LAST>
__global__ __launch_bounds__(256) void sample_kernel(
    const float* __restrict__ feat,
    const float* __restrict__ points,   // [NVOX][3]
    const float* __restrict__ proj,     // [NV][4][4]
    float* __restrict__ out)            // [C][NX][NY][NZ]
{
  const int wave = threadIdx.x >> 6;
  const int lane = threadIdx.x & 63;
  const int n = blockIdx.x * 4 + wave;   // grid sized exactly: NVOX/4 blocks

  const float x = points[n * 3 + 0];
  const float y = points[n * 3 + 1];
  const float z = points[n * 3 + 2];

  float acc = 0.0f;
  int cnt = 0;

#pragma unroll
  for (int v = 0; v < NV; ++v) {
    const float* M = proj + v * 16;
    const float cx = M[0] * x + M[1] * y + M[2]  * z + M[3];
    const float cy = M[4] * x + M[5] * y + M[6]  * z + M[7];
    const float cz = M[8] * x + M[9] * y + M[10] * z + M[11];

    // d_safe per reference
    const float dz = (fabsf(cz) > 1e-6f) ? cz : 1e-6f;
    const float u  = cx / dz;
    const float vv = cy / dz;

    const bool valid = (cz > 0.0f) && (u > 0.0f) && (u < 1600.0f) &&
                       (vv > 0.0f) && (vv < 928.0f);
    if (!valid) continue;   // wave-uniform branch
    cnt++;

    const float px = u * INV8 - 0.5f;
    const float py = vv * INV8 - 0.5f;
    const float fx0 = floorf(px);
    const float fy0 = floorf(py);
    const float wx1 = px - fx0;
    const float wy1 = py - fy0;
    const float wx0 = 1.0f - wx1;
    const float wy0 = 1.0f - wy1;
    const int ix0 = (int)fx0;
    const int iy0 = (int)fy0;

    const float w00 = wx0 * wy0;
    const float w10 = wx1 * wy0;
    const float w01 = wx0 * wy1;
    const float w11 = wx1 * wy1;

    const float* basev = CHANNELS_LAST
        ? feat + (size_t)v * PLANE * NC
        : feat + ((size_t)v * NC + lane) * PLANE;

    auto tap = [&](int xi, int yi, float w) {
      if (xi >= 0 && xi < WFv && yi >= 0 && yi < HFv) {   // wave-uniform
        const int pix = yi * WFv + xi;
        const float val = CHANNELS_LAST ? basev[(size_t)pix * NC + lane]
                                        : basev[pix];
        acc += w * val;
      }
    };
    tap(ix0,     iy0,     w00);
    tap(ix0 + 1, iy0,     w10);
    tap(ix0,     iy0 + 1, w01);
    tap(ix0 + 1, iy0 + 1, w11);
  }

  const float scale = (cnt > 0) ? (1.0f / (float)cnt) : 0.0f;

  // n = iz*(NY*NX) + iy*NX + ix ; out[c][ix][iy][iz]
  const int iz  = n >> 14;        // / (128*128)
  const int rem = n & 16383;
  const int iy  = rem >> 7;
  const int ix  = rem & 127;
  out[(((size_t)lane * NXv + ix) * NYv + iy) * NZv + iz] = acc * scale;
}

extern "C" void kernel_launch(void* const* d_in, const int* in_sizes, int n_in,
                              void* d_out, int out_size, void* d_ws, size_t ws_size,
                              hipStream_t stream) {
  const float* x_fov  = (const float*)d_in[0];  // [1,6,64,116,200] f32
  const float* points = (const float*)d_in[1];  // [131072,3] f32
  const float* proj   = (const float*)d_in[2];  // [6,4,4] f32
  float* out = (float*)d_out;                   // [1,64,128,128,8] f32

  const size_t need = (size_t)NV * NC * PLANE * sizeof(float);
  if (ws_size >= need) {
    float* ft = (float*)d_ws;
    dim3 tgrid((PLANE + 63) / 64, NV);
    transpose_feat<<<tgrid, 256, 0, stream>>>(x_fov, ft);
    sample_kernel<true><<<NVOX / 4, 256, 0, stream>>>(ft, points, proj, out);
  } else {
    sample_kernel<false><<<NVOX / 4, 256, 0, stream>>>(x_fov, points, proj, out);
  }
}

// Round 2
// 156.380 us; speedup vs baseline: 1.4933x; 1.4933x over previous
//
#include <hip/hip_runtime.h>
#include <hip/hip_bf16.h>

// Problem constants (from reference)
#define NXv 128
#define NYv 128
#define NZv 8
#define NVOX (NXv * NYv * NZv)   // 131072
#define NV 6
#define NC 64
#define HFv 116
#define WFv 200
#define PLANE (HFv * WFv)        // 23200

#define FT_FLOATS ((size_t)NV * NC * PLANE)      // 8,908,800
#define PD_FLOATS ((size_t)NVOX * NV * 8)        // 6,291,456  (per (n,v): 4 pix + 4 wgt)
#define INVC_FLOATS ((size_t)NVOX)

// ---------------------------------------------------------------------------
// K1: Transpose [V][C][PLANE] -> [V][PLANE][C]  (channels-last for gathers)
// ---------------------------------------------------------------------------
__global__ __launch_bounds__(256) void transpose_feat(
    const float* __restrict__ in, float* __restrict__ out) {
  __shared__ float tile[64][65];
  const int v  = blockIdx.y;
  const int p0 = blockIdx.x * 64;
  const float* src = in  + (size_t)v * NC * PLANE;
  float*       dst = out + (size_t)v * PLANE * NC;
  const int t = threadIdx.x;

#pragma unroll
  for (int i = 0; i < 16; ++i) {
    int l = i * 256 + t;
    int c = l >> 6;
    int p = l & 63;
    int pp = p0 + p;
    tile[c][p] = (pp < PLANE) ? src[c * PLANE + pp] : 0.0f;
  }
  __syncthreads();
#pragma unroll
  for (int i = 0; i < 16; ++i) {
    int l = i * 256 + t;
    int p = l >> 6;
    int c = l & 63;
    int pp = p0 + p;
    if (pp < PLANE) dst[(size_t)pp * NC + c] = tile[c][p];
  }
}

// ---------------------------------------------------------------------------
// K2: Per-point projection precompute. ONE THREAD PER POINT.
// Emits per (n,v): float4{pix00|sentinel, pix10, pix01, pix11 (as int bits)},
//                  float4{w00,w10,w01,w11} premasked by inb*valid.
// Plus invc[n] = cnt>0 ? 1/cnt : 0.
// ---------------------------------------------------------------------------
__global__ __launch_bounds__(256) void precompute_proj(
    const float* __restrict__ points,
    const float* __restrict__ proj,
    float4* __restrict__ pdata,
    float* __restrict__ invc) {
  const int n = blockIdx.x * 256 + threadIdx.x;
  const float x = points[n * 3 + 0];
  const float y = points[n * 3 + 1];
  const float z = points[n * 3 + 2];
  float cnt = 0.0f;

#pragma unroll
  for (int v = 0; v < NV; ++v) {
    const float* M = proj + v * 16;
    const float cx = M[0] * x + M[1] * y + M[2]  * z + M[3];
    const float cy = M[4] * x + M[5] * y + M[6]  * z + M[7];
    const float cz = M[8] * x + M[9] * y + M[10] * z + M[11];

    const float dz = (fabsf(cz) > 1e-6f) ? cz : 1e-6f;
    const float u  = cx / dz;
    const float vv = cy / dz;

    const bool valid = (cz > 0.0f) && (u > 0.0f) && (u < 1600.0f) &&
                       (vv > 0.0f) && (vv < 928.0f);
    cnt += valid ? 1.0f : 0.0f;

    // match reference: u / PAD_W * WF - 0.5   (PAD_W/WF == 8)
    const float px = u  / 1600.0f * 200.0f - 0.5f;
    const float py = vv / 928.0f  * 116.0f - 0.5f;
    const float fx0 = floorf(px);
    const float fy0 = floorf(py);
    const float wx1 = px - fx0;
    const float wy1 = py - fy0;
    const float wx0 = 1.0f - wx1;
    const float wy0 = 1.0f - wy1;
    const int ix0 = (int)fx0;
    const int iy0 = (int)fy0;

    int   pix[4];
    float wgt[4];
    const int   xs[4] = {ix0, ix0 + 1, ix0,     ix0 + 1};
    const int   ys[4] = {iy0, iy0,     iy0 + 1, iy0 + 1};
    const float ww[4] = {wx0 * wy0, wx1 * wy0, wx0 * wy1, wx1 * wy1};
#pragma unroll
    for (int k = 0; k < 4; ++k) {
      const int xi = xs[k], yi = ys[k];
      const bool inb = (xi >= 0) && (xi < WFv) && (yi >= 0) && (yi < HFv);
      const int xc = min(max(xi, 0), WFv - 1);
      const int yc = min(max(yi, 0), HFv - 1);
      pix[k] = yc * WFv + xc;
      wgt[k] = (inb && valid) ? ww[k] : 0.0f;
    }

    float4 a, w4;
    a.x = __int_as_float(valid ? pix[0] : -1);  // sentinel: whole view invalid
    a.y = __int_as_float(pix[1]);
    a.z = __int_as_float(pix[2]);
    a.w = __int_as_float(pix[3]);
    w4.x = wgt[0]; w4.y = wgt[1]; w4.z = wgt[2]; w4.w = wgt[3];
    pdata[(size_t)n * (NV * 2) + v * 2 + 0] = a;
    pdata[(size_t)n * (NV * 2) + v * 2 + 1] = w4;
  }
  invc[n] = (cnt > 0.0f) ? (1.0f / cnt) : 0.0f;
}

// ---------------------------------------------------------------------------
// K3: Gather + LDS-transposed coalesced store.
// Block = 64 output-contiguous points: fixed ix, iy in [iy0,iy0+8), iz in [0,8).
// 4 waves x 16 points each, lane = channel. Output per (c, block): 64
// consecutive floats -> 256 B coalesced store per wave.
// ---------------------------------------------------------------------------
__global__ __launch_bounds__(256) void gather_kernel(
    const float* __restrict__ feat,    // [V][PLANE][C]
    const float4* __restrict__ pdata,  // [N][V*2]
    const float* __restrict__ invc,    // [N]
    float* __restrict__ out) {         // [C][NX][NY][NZ]
  __shared__ float tile[64][65];
  const int b    = blockIdx.x;       // 0..2047
  const int ix   = b & 127;
  const int iy0g = (b >> 7) << 3;
  const int t    = threadIdx.x;
  const int lane = t & 63;
  const int wave = t >> 6;

#pragma unroll 1
  for (int k = 0; k < 16; ++k) {
    const int s  = wave * 16 + k;
    const int j  = s >> 3;
    const int iz = s & 7;
    const int n  = iz * (NXv * NYv) + (iy0g + j) * NXv + ix;

    const float4* pd = pdata + (size_t)n * (NV * 2);
    const float s_inv = invc[n];
    float acc = 0.0f;

#pragma unroll
    for (int v = 0; v < NV; ++v) {
      const float4 a  = pd[v * 2 + 0];
      const float4 w4 = pd[v * 2 + 1];
      const int p00 = __float_as_int(a.x);
      if (p00 >= 0) {   // wave-uniform (all lanes read same value)
        const int p10 = __float_as_int(a.y);
        const int p01 = __float_as_int(a.z);
        const int p11 = __float_as_int(a.w);
        const float* fb = feat + (size_t)v * PLANE * NC + lane;
        acc = fmaf(w4.x, fb[p00 * NC], acc);
        acc = fmaf(w4.y, fb[p10 * NC], acc);
        acc = fmaf(w4.z, fb[p01 * NC], acc);
        acc = fmaf(w4.w, fb[p11 * NC], acc);
      }
    }
    tile[s][lane] = acc * s_inv;
  }

  __syncthreads();

  // Cooperative coalesced store: wave w writes channels {i*4+w}, 64 floats each.
  const size_t obase = (size_t)ix * (NYv * NZv) + (size_t)iy0g * NZv + lane;
#pragma unroll
  for (int i = 0; i < 16; ++i) {
    const int c = i * 4 + wave;
    out[(size_t)c * NVOX + obase] = tile[lane][c];
  }
}

// ---------------------------------------------------------------------------
// Fallback (round-1 style) if workspace is too small.
// ---------------------------------------------------------------------------
template <bool CHANNELS_LAST>
__global__ __launch_bounds__(256) void sample_kernel(
    const float* __restrict__ feat,
    const float* __restrict__ points,
    const float* __restrict__ proj,
    float* __restrict__ out) {
  const int wave = threadIdx.x >> 6;
  const int lane = threadIdx.x & 63;
  const int n = blockIdx.x * 4 + wave;

  const float x = points[n * 3 + 0];
  const float y = points[n * 3 + 1];
  const float z = points[n * 3 + 2];

  float acc = 0.0f;
  int cnt = 0;

#pragma unroll
  for (int v = 0; v < NV; ++v) {
    const float* M = proj + v * 16;
    const float cx = M[0] * x + M[1] * y + M[2]  * z + M[3];
    const float cy = M[4] * x + M[5] * y + M[6]  * z + M[7];
    const float cz = M[8] * x + M[9] * y + M[10] * z + M[11];
    const float dz = (fabsf(cz) > 1e-6f) ? cz : 1e-6f;
    const float u  = cx / dz;
    const float vv = cy / dz;
    const bool valid = (cz > 0.0f) && (u > 0.0f) && (u < 1600.0f) &&
                       (vv > 0.0f) && (vv < 928.0f);
    if (!valid) continue;
    cnt++;
    const float px = u  / 1600.0f * 200.0f - 0.5f;
    const float py = vv / 928.0f  * 116.0f - 0.5f;
    const float fx0 = floorf(px);
    const float fy0 = floorf(py);
    const float wx1 = px - fx0;
    const float wy1 = py - fy0;
    const float wx0 = 1.0f - wx1;
    const float wy0 = 1.0f - wy1;
    const int ix0 = (int)fx0;
    const int iy0 = (int)fy0;
    const float w00 = wx0 * wy0, w10 = wx1 * wy0, w01 = wx0 * wy1, w11 = wx1 * wy1;
    const float* basev = CHANNELS_LAST
        ? feat + (size_t)v * PLANE * NC
        : feat + ((size_t)v * NC + lane) * PLANE;
    auto tap = [&](int xi, int yi, float w) {
      if (xi >= 0 && xi < WFv && yi >= 0 && yi < HFv) {
        const int pix = yi * WFv + xi;
        const float val = CHANNELS_LAST ? basev[(size_t)pix * NC + lane]
                                        : basev[pix];
        acc += w * val;
      }
    };
    tap(ix0,     iy0,     w00);
    tap(ix0 + 1, iy0,     w10);
    tap(ix0,     iy0 + 1, w01);
    tap(ix0 + 1, iy0 + 1, w11);
  }

  const float scale = (cnt > 0) ? (1.0f / (float)cnt) : 0.0f;
  const int iz  = n >> 14;
  const int rem = n & 16383;
  const int iy  = rem >> 7;
  const int ixx = rem & 127;
  out[(((size_t)lane * NXv + ixx) * NYv + iy) * NZv + iz] = acc * scale;
}

extern "C" void kernel_launch(void* const* d_in, const int* in_sizes, int n_in,
                              void* d_out, int out_size, void* d_ws, size_t ws_size,
                              hipStream_t stream) {
  const float* x_fov  = (const float*)d_in[0];  // [1,6,64,116,200] f32
  const float* points = (const float*)d_in[1];  // [131072,3] f32
  const float* proj   = (const float*)d_in[2];  // [6,4,4] f32
  float* out = (float*)d_out;                   // [1,64,128,128,8] f32

  const size_t ft_bytes   = FT_FLOATS * sizeof(float);    // 35,635,200
  const size_t pd_bytes   = PD_FLOATS * sizeof(float);    // 25,165,824
  const size_t invc_bytes = INVC_FLOATS * sizeof(float);  //    524,288

  if (ws_size >= ft_bytes + pd_bytes + invc_bytes) {
    float*  ft = (float*)d_ws;
    float4* pd = (float4*)((char*)d_ws + ft_bytes);
    float*  ic = (float*)((char*)d_ws + ft_bytes + pd_bytes);

    dim3 tgrid((PLANE + 63) / 64, NV);
    transpose_feat<<<tgrid, 256, 0, stream>>>(x_fov, ft);
    precompute_proj<<<NVOX / 256, 256, 0, stream>>>(points, proj, pd, ic);
    gather_kernel<<<(NXv * NYv / 8), 256, 0, stream>>>(ft, pd, ic, out);
  } else if (ws_size >= ft_bytes) {
    float* ft = (float*)d_ws;
    dim3 tgrid((PLANE + 63) / 64, NV);
    transpose_feat<<<tgrid, 256, 0, stream>>>(x_fov, ft);
    sample_kernel<true><<<NVOX / 4, 256, 0, stream>>>(ft, points, proj, out);
  } else {
    sample_kernel<false><<<NVOX / 4, 256, 0, stream>>>(x_fov, points, proj, out);
  }
}

// Round 3
// 123.216 us; speedup vs baseline: 1.8952x; 1.2692x over previous
//
#include <hip/hip_runtime.h>
#include <hip/hip_bf16.h>
#include <hip/hip_fp16.h>

// Problem constants
#define NXv 128
#define NYv 128
#define NZv 8
#define NVOX (NXv * NYv * NZv)   // 131072
#define NV 6
#define NC 64
#define HFv 116
#define WFv 200
#define PLANE (HFv * WFv)        // 23200

// Workspace partitions
#define FT_BYTES   ((size_t)NV * PLANE * NC * 2)        // 17,817,600 (bf16 channels-last)
#define PD_BYTES   ((size_t)NVOX * NV * 16)             // 12,582,912 (uint4 per (n,v))
#define INVC_BYTES ((size_t)NVOX * 4)

// ---- small helpers ---------------------------------------------------------
__device__ inline unsigned short f2bf(float f) {   // f32 -> bf16 bits, RNE
  unsigned int x = __float_as_uint(f);
  unsigned int r = x + 0x7fffu + ((x >> 16) & 1u);
  return (unsigned short)(r >> 16);
}
__device__ inline float bf_lo(unsigned int q) { return __uint_as_float(q << 16); }
__device__ inline float bf_hi(unsigned int q) { return __uint_as_float(q & 0xffff0000u); }

__device__ inline unsigned short f2h_bits(float f) {
  __half h = __float2half(f);
  return *reinterpret_cast<unsigned short*>(&h);
}
__device__ inline float h_bits2f(unsigned short u) {
  __half_raw r; r.x = u;
  __half h = *reinterpret_cast<__half*>(&r);
  return __half2float(h);
}

// ---------------------------------------------------------------------------
// K1: Transpose+convert [V][C][PLANE] f32 -> [V][PLANE][C] bf16.
// Tile = 64 channels x 64 pixels. float4 global reads (1KB/wave-instr),
// packed 2xbf16 (uint) stores (256B/wave-instr).
// ---------------------------------------------------------------------------
__global__ __launch_bounds__(256) void transpose_feat_bf16(
    const float* __restrict__ in, unsigned int* __restrict__ out32) {
  __shared__ float tile[64][65];                 // [pixel][channel]
  const int v  = blockIdx.y;
  const int p0 = blockIdx.x * 64;
  const float* src = in + (size_t)v * NC * PLANE;
  unsigned int* dst = out32 + (size_t)v * PLANE * (NC / 2);
  const int t = threadIdx.x;

  // Phase 1: read float4 along pixel dim, scatter into LDS [p][c].
#pragma unroll
  for (int i = 0; i < 4; ++i) {
    const int idx = i * 256 + t;                 // [0,1024)
    const int c  = idx >> 4;                     // 0..63
    const int p4 = idx & 15;                     // 0..15 (x4 pixels)
    const int pp = p0 + p4 * 4;
    if (pp < PLANE) {                            // PLANE%4==0 -> full float4 ok
      const float4 f = *(const float4*)(src + (size_t)c * PLANE + pp);
      tile[p4 * 4 + 0][c] = f.x;
      tile[p4 * 4 + 1][c] = f.y;
      tile[p4 * 4 + 2][c] = f.z;
      tile[p4 * 4 + 3][c] = f.w;
    }
  }
  __syncthreads();

  // Phase 2: write packed channel-pairs, contiguous per pixel.
#pragma unroll
  for (int i = 0; i < 8; ++i) {
    const int idx = i * 256 + t;                 // [0,2048)
    const int p   = idx >> 5;                    // 0..63
    const int c2  = idx & 31;                    // 0..31
    const int pp  = p0 + p;
    if (pp < PLANE) {
      const unsigned int lo = f2bf(tile[p][c2 * 2 + 0]);
      const unsigned int hi = f2bf(tile[p][c2 * 2 + 1]);
      dst[(size_t)pp * 32 + c2] = lo | (hi << 16);
    }
  }
}

// ---------------------------------------------------------------------------
// K2: Per-point projection precompute (one thread per point).
// Record per (n,v): uint4 { pix0|valid<<15 | pix1<<16, pix2|pix3<<16,
//                           h(w0)|h(w1)<<16, h(w2)|h(w3)<<16 }
// Written in gather-block order: rp = b*64+s, b=(iy>>3)*128+ix, s=(iy&7)*8+iz.
// ---------------------------------------------------------------------------
__global__ __launch_bounds__(256) void precompute_proj(
    const float* __restrict__ points,
    const float* __restrict__ proj,
    uint4* __restrict__ pdata_r,
    float* __restrict__ invc_r) {
  const int n = blockIdx.x * 256 + threadIdx.x;
  const float x = points[n * 3 + 0];
  const float y = points[n * 3 + 1];
  const float z = points[n * 3 + 2];

  const int iz  = n >> 14;
  const int rem = n & 16383;
  const int iy  = rem >> 7;
  const int ix  = rem & 127;
  const int rp  = ((iy >> 3) * 128 + ix) * 64 + ((iy & 7) * 8 + iz);

  float cnt = 0.0f;

#pragma unroll
  for (int v = 0; v < NV; ++v) {
    const float* M = proj + v * 16;
    const float cx = M[0] * x + M[1] * y + M[2]  * z + M[3];
    const float cy = M[4] * x + M[5] * y + M[6]  * z + M[7];
    const float cz = M[8] * x + M[9] * y + M[10] * z + M[11];

    const float dz = (fabsf(cz) > 1e-6f) ? cz : 1e-6f;
    const float u  = cx / dz;
    const float vv = cy / dz;

    const bool valid = (cz > 0.0f) && (u > 0.0f) && (u < 1600.0f) &&
                       (vv > 0.0f) && (vv < 928.0f);
    cnt += valid ? 1.0f : 0.0f;

    const float px = u  / 1600.0f * 200.0f - 0.5f;
    const float py = vv / 928.0f  * 116.0f - 0.5f;
    const float fx0 = floorf(px);
    const float fy0 = floorf(py);
    const float wx1 = px - fx0;
    const float wy1 = py - fy0;
    const float wx0 = 1.0f - wx1;
    const float wy0 = 1.0f - wy1;
    const int ix0 = (int)fx0;
    const int iy0 = (int)fy0;

    unsigned int pix[4];
    unsigned short wh[4];
    const int   xs[4] = {ix0, ix0 + 1, ix0,     ix0 + 1};
    const int   ys[4] = {iy0, iy0,     iy0 + 1, iy0 + 1};
    const float ww[4] = {wx0 * wy0, wx1 * wy0, wx0 * wy1, wx1 * wy1};
#pragma unroll
    for (int k = 0; k < 4; ++k) {
      const int xi = xs[k], yi = ys[k];
      const bool inb = (xi >= 0) && (xi < WFv) && (yi >= 0) && (yi < HFv);
      const int xc = min(max(xi, 0), WFv - 1);
      const int yc = min(max(yi, 0), HFv - 1);
      pix[k] = (unsigned int)(yc * WFv + xc);             // < 23200 < 2^15
      wh[k]  = f2h_bits((inb && valid) ? ww[k] : 0.0f);
    }

    uint4 rec;
    rec.x = pix[0] | (valid ? 0x8000u : 0u) | (pix[1] << 16);
    rec.y = pix[2] | (pix[3] << 16);
    rec.z = (unsigned int)wh[0] | ((unsigned int)wh[1] << 16);
    rec.w = (unsigned int)wh[2] | ((unsigned int)wh[3] << 16);
    pdata_r[(size_t)rp * NV + v] = rec;
  }
  invc_r[rp] = (cnt > 0.0f) ? (1.0f / cnt) : 0.0f;
}

// ---------------------------------------------------------------------------
// K3: Gather. Block = 64 output-contiguous points (fixed ix, 8 iy, 8 iz).
// pdata staged to LDS (coalesced 6KB). Wave processes 2 points at a time:
// lane = (half:1, cpair:5). Tap load = uint (2 packed bf16 channels).
// LDS-transposed coalesced output stores.
// ---------------------------------------------------------------------------
__global__ __launch_bounds__(256) void gather_kernel(
    const unsigned int* __restrict__ feat32,  // [V][PLANE][32] packed bf16x2
    const uint4* __restrict__ pdata_r,        // [2048][64][NV]
    const float* __restrict__ invc_r,         // [2048][64]
    float* __restrict__ out) {                // [C][NX][NY][NZ]
  __shared__ float tile[64][65];
  __shared__ uint4 pdl[64 * NV];
  __shared__ float invl[64];

  const int b    = blockIdx.x;               // 0..2047
  const int ix   = b & 127;
  const int iy0g = (b >> 7) << 3;
  const int t    = threadIdx.x;
  const int lane = t & 63;
  const int wave = t >> 6;
  const int half = lane >> 5;                // 0/1: which of the 2 points
  const int c2   = lane & 31;                // channel pair

  // Stage this block's pdata (6KB contiguous) + invc into LDS.
  {
    const uint4* src = pdata_r + (size_t)b * 64 * NV;
    for (int i = t; i < 64 * NV; i += 256) pdl[i] = src[i];
    if (t < 64) invl[t] = invc_r[(size_t)b * 64 + t];
  }
  __syncthreads();

#pragma unroll 1
  for (int k = 0; k < 8; ++k) {
    const int sl = wave * 16 + k * 2 + half;   // slot 0..63
    float accx = 0.0f, accy = 0.0f;

#pragma unroll
    for (int v = 0; v < NV; ++v) {
      const uint4 rec = pdl[sl * NV + v];
      const bool vld = (rec.x & 0x8000u) != 0;   // uniform per half-wave
      if (vld) {
        const unsigned int p00 = rec.x & 0x7fffu;
        const unsigned int p10 = rec.x >> 16;
        const unsigned int p01 = rec.y & 0xffffu;
        const unsigned int p11 = rec.y >> 16;
        const float w0 = h_bits2f((unsigned short)(rec.z & 0xffffu));
        const float w1 = h_bits2f((unsigned short)(rec.z >> 16));
        const float w2 = h_bits2f((unsigned short)(rec.w & 0xffffu));
        const float w3 = h_bits2f((unsigned short)(rec.w >> 16));

        const unsigned int* fb = feat32 + (size_t)v * PLANE * 32 + c2;
        const unsigned int q0 = fb[(size_t)p00 * 32];
        const unsigned int q1 = fb[(size_t)p10 * 32];
        const unsigned int q2 = fb[(size_t)p01 * 32];
        const unsigned int q3 = fb[(size_t)p11 * 32];

        accx = fmaf(w0, bf_lo(q0), accx);  accy = fmaf(w0, bf_hi(q0), accy);
        accx = fmaf(w1, bf_lo(q1), accx);  accy = fmaf(w1, bf_hi(q1), accy);
        accx = fmaf(w2, bf_lo(q2), accx);  accy = fmaf(w2, bf_hi(q2), accy);
        accx = fmaf(w3, bf_lo(q3), accx);  accy = fmaf(w3, bf_hi(q3), accy);
      }
    }

    const float inv = invl[sl];
    tile[sl][c2 * 2 + 0] = accx * inv;
    tile[sl][c2 * 2 + 1] = accy * inv;
  }

  __syncthreads();

  // Coalesced store: wave w writes channels {i*4+w}, 64 consecutive floats.
  const size_t obase = (size_t)ix * (NYv * NZv) + (size_t)iy0g * NZv + lane;
#pragma unroll
  for (int i = 0; i < 16; ++i) {
    const int c = i * 4 + wave;
    out[(size_t)c * NVOX + obase] = tile[lane][c];
  }
}

// ---------------------------------------------------------------------------
// Fallback: direct channel-major sampling (no workspace).
// ---------------------------------------------------------------------------
__global__ __launch_bounds__(256) void sample_fallback(
    const float* __restrict__ feat,
    const float* __restrict__ points,
    const float* __restrict__ proj,
    float* __restrict__ out) {
  const int wave = threadIdx.x >> 6;
  const int lane = threadIdx.x & 63;
  const int n = blockIdx.x * 4 + wave;

  const float x = points[n * 3 + 0];
  const float y = points[n * 3 + 1];
  const float z = points[n * 3 + 2];

  float acc = 0.0f;
  int cnt = 0;

#pragma unroll
  for (int v = 0; v < NV; ++v) {
    const float* M = proj + v * 16;
    const float cx = M[0] * x + M[1] * y + M[2]  * z + M[3];
    const float cy = M[4] * x + M[5] * y + M[6]  * z + M[7];
    const float cz = M[8] * x + M[9] * y + M[10] * z + M[11];
    const float dz = (fabsf(cz) > 1e-6f) ? cz : 1e-6f;
    const float u  = cx / dz;
    const float vv = cy / dz;
    const bool valid = (cz > 0.0f) && (u > 0.0f) && (u < 1600.0f) &&
                       (vv > 0.0f) && (vv < 928.0f);
    if (!valid) continue;
    cnt++;
    const float px = u  / 1600.0f * 200.0f - 0.5f;
    const float py = vv / 928.0f  * 116.0f - 0.5f;
    const float fx0 = floorf(px);
    const float fy0 = floorf(py);
    const float wx1 = px - fx0;
    const float wy1 = py - fy0;
    const float wx0 = 1.0f - wx1;
    const float wy0 = 1.0f - wy1;
    const int ix0 = (int)fx0;
    const int iy0 = (int)fy0;
    const float w00 = wx0 * wy0, w10 = wx1 * wy0, w01 = wx0 * wy1, w11 = wx1 * wy1;
    const float* basev = feat + ((size_t)v * NC + lane) * PLANE;
    auto tap = [&](int xi, int yi, float w) {
      if (xi >= 0 && xi < WFv && yi >= 0 && yi < HFv)
        acc += w * basev[yi * WFv + xi];
    };
    tap(ix0,     iy0,     w00);
    tap(ix0 + 1, iy0,     w10);
    tap(ix0,     iy0 + 1, w01);
    tap(ix0 + 1, iy0 + 1, w11);
  }

  const float scale = (cnt > 0) ? (1.0f / (float)cnt) : 0.0f;
  const int iz  = n >> 14;
  const int rem = n & 16383;
  const int iy  = rem >> 7;
  const int ixx = rem & 127;
  out[(((size_t)lane * NXv + ixx) * NYv + iy) * NZv + iz] = acc * scale;
}

extern "C" void kernel_launch(void* const* d_in, const int* in_sizes, int n_in,
                              void* d_out, int out_size, void* d_ws, size_t ws_size,
                              hipStream_t stream) {
  const float* x_fov  = (const float*)d_in[0];  // [1,6,64,116,200] f32
  const float* points = (const float*)d_in[1];  // [131072,3] f32
  const float* proj   = (const float*)d_in[2];  // [6,4,4] f32
  float* out = (float*)d_out;                   // [1,64,128,128,8] f32

  if (ws_size >= FT_BYTES + PD_BYTES + INVC_BYTES) {
    unsigned int* ft = (unsigned int*)d_ws;
    uint4* pd = (uint4*)((char*)d_ws + FT_BYTES);
    float* ic = (float*)((char*)d_ws + FT_BYTES + PD_BYTES);

    dim3 tgrid((PLANE + 63) / 64, NV);
    transpose_feat_bf16<<<tgrid, 256, 0, stream>>>(x_fov, ft);
    precompute_proj<<<NVOX / 256, 256, 0, stream>>>(points, proj, pd, ic);
    gather_kernel<<<NXv * NYv / 8, 256, 0, stream>>>(ft, pd, ic, out);
  } else {
    sample_fallback<<<NVOX / 4, 256, 0, stream>>>(x_fov, points, proj, out);
  }
}

// Round 4
// 109.406 us; speedup vs baseline: 2.1344x; 1.1262x over previous
//
#include <hip/hip_runtime.h>
#include <hip/hip_bf16.h>
#include <hip/hip_fp16.h>

// Problem constants
#define NXv 128
#define NYv 128
#define NZv 8
#define NVOX (NXv * NYv * NZv)   // 131072
#define NV 6
#define NC 64
#define HFv 116
#define WFv 200
#define PLANE (HFv * WFv)        // 23200

#define FT_BYTES ((size_t)NV * PLANE * NC * 2)   // 17,817,600 (bf16 channels-last)

// ---- helpers ---------------------------------------------------------------
__device__ inline unsigned short f2bf(float f) {   // f32 -> bf16 bits, RNE
  unsigned int x = __float_as_uint(f);
  unsigned int r = x + 0x7fffu + ((x >> 16) & 1u);
  return (unsigned short)(r >> 16);
}
__device__ inline float bf_lo(unsigned int q) { return __uint_as_float(q << 16); }
__device__ inline float bf_hi(unsigned int q) { return __uint_as_float(q & 0xffff0000u); }

__device__ inline unsigned short f2h_bits(float f) {
  __half h = __float2half(f);
  return *reinterpret_cast<unsigned short*>(&h);
}
__device__ inline float h_bits2f(unsigned short u) {
  __half_raw r; r.x = u;
  __half h = *reinterpret_cast<__half*>(&r);
  return __half2float(h);
}

// ---------------------------------------------------------------------------
// K1: Transpose+convert [V][C][PLANE] f32 -> [V][PLANE][C] bf16 (packed).
// float4 global reads; uint2 (4 packed bf16) stores, 512B/wave-instr.
// ---------------------------------------------------------------------------
__global__ __launch_bounds__(256) void transpose_feat_bf16(
    const float* __restrict__ in, unsigned int* __restrict__ out32) {
  __shared__ float tile[64][65];                 // [pixel][channel]
  const int v  = blockIdx.y;
  const int p0 = blockIdx.x * 64;
  const float* src = in + (size_t)v * NC * PLANE;
  unsigned int* dst = out32 + (size_t)v * PLANE * (NC / 2);
  const int t = threadIdx.x;

  // Phase 1: float4 reads along pixel dim -> LDS [p][c].
#pragma unroll
  for (int i = 0; i < 4; ++i) {
    const int idx = i * 256 + t;                 // [0,1024)
    const int c  = idx >> 4;                     // 0..63
    const int p4 = idx & 15;                     // 0..15
    const int pp = p0 + p4 * 4;
    if (pp < PLANE) {                            // PLANE%4==0 -> full float4 ok
      const float4 f = *(const float4*)(src + (size_t)c * PLANE + pp);
      tile[p4 * 4 + 0][c] = f.x;
      tile[p4 * 4 + 1][c] = f.y;
      tile[p4 * 4 + 2][c] = f.z;
      tile[p4 * 4 + 3][c] = f.w;
    }
  }
  __syncthreads();

  // Phase 2: write packed channel-quads (uint2) contiguous per pixel.
#pragma unroll
  for (int i = 0; i < 4; ++i) {
    const int idx = i * 256 + t;                 // [0,1024)
    const int p   = idx >> 4;                    // 0..63
    const int c4  = idx & 15;                    // 0..15
    const int pp  = p0 + p;
    if (pp < PLANE) {
      uint2 w;
      w.x = (unsigned int)f2bf(tile[p][c4 * 4 + 0]) |
            ((unsigned int)f2bf(tile[p][c4 * 4 + 1]) << 16);
      w.y = (unsigned int)f2bf(tile[p][c4 * 4 + 2]) |
            ((unsigned int)f2bf(tile[p][c4 * 4 + 3]) << 16);
      *(uint2*)(dst + (size_t)pp * 32 + c4 * 2) = w;
    }
  }
}

// ---------------------------------------------------------------------------
// K2: Fused projection + gather + coalesced store.
// Block = 64 output-contiguous points (fixed ix, 8 iy, 8 iz).
// Phase A: 384 (slot,view) projection tasks over 256 threads -> LDS recs.
// Phase B: 8 points/wave, lane=(point:3,chunk:3); tap = global_load_dwordx4
//          (8 bf16x2 channels), 1KB per wave-instruction.
// Phase C: LDS-transposed coalesced output stores.
// ---------------------------------------------------------------------------
__global__ __launch_bounds__(256) void gather_fused(
    const uint4* __restrict__ feat4,    // [V][PLANE][8] uint4 (64 bf16 ch)
    const float* __restrict__ points,   // [NVOX][3]
    const float* __restrict__ proj,     // [NV][4][4]
    float* __restrict__ out) {          // [C][NX][NY][NZ]
  __shared__ float tile[64][65];
  __shared__ uint4 pdl[64 * NV];
  __shared__ float invl[64];
  __shared__ float projl[96];

  const int b    = blockIdx.x;          // 0..2047
  const int ix   = b & 127;
  const int iy0g = (b >> 7) << 3;
  const int t    = threadIdx.x;
  const int lane = t & 63;
  const int wave = t >> 6;

  if (t < 96) projl[t] = proj[t];
  if (t < 64) invl[t] = 0.0f;
  __syncthreads();

  // ---- Phase A: projections ----
  for (int task = t; task < 64 * NV; task += 256) {
    const int slot = task / NV;
    const int v    = task - slot * NV;
    const int j    = slot >> 3;
    const int iz   = slot & 7;
    const int n    = iz * (NXv * NYv) + (iy0g + j) * NXv + ix;

    const float x = points[n * 3 + 0];
    const float y = points[n * 3 + 1];
    const float z = points[n * 3 + 2];

    const float* M = projl + v * 16;
    const float cx = M[0] * x + M[1] * y + M[2]  * z + M[3];
    const float cy = M[4] * x + M[5] * y + M[6]  * z + M[7];
    const float cz = M[8] * x + M[9] * y + M[10] * z + M[11];

    const float dz = (fabsf(cz) > 1e-6f) ? cz : 1e-6f;
    const float u  = cx / dz;
    const float vv = cy / dz;

    const bool valid = (cz > 0.0f) && (u > 0.0f) && (u < 1600.0f) &&
                       (vv > 0.0f) && (vv < 928.0f);
    if (valid) atomicAdd(&invl[slot], 1.0f);

    const float px = u  / 1600.0f * 200.0f - 0.5f;
    const float py = vv / 928.0f  * 116.0f - 0.5f;
    const float fx0 = floorf(px);
    const float fy0 = floorf(py);
    const float wx1 = px - fx0;
    const float wy1 = py - fy0;
    const float wx0 = 1.0f - wx1;
    const float wy0 = 1.0f - wy1;
    const int ix0 = (int)fx0;
    const int iy0 = (int)fy0;

    unsigned int pix[4];
    unsigned short wh[4];
    const int   xs[4] = {ix0, ix0 + 1, ix0,     ix0 + 1};
    const int   ys[4] = {iy0, iy0,     iy0 + 1, iy0 + 1};
    const float ww[4] = {wx0 * wy0, wx1 * wy0, wx0 * wy1, wx1 * wy1};
#pragma unroll
    for (int k = 0; k < 4; ++k) {
      const int xi = xs[k], yi = ys[k];
      const bool inb = (xi >= 0) && (xi < WFv) && (yi >= 0) && (yi < HFv);
      const int xc = min(max(xi, 0), WFv - 1);
      const int yc = min(max(yi, 0), HFv - 1);
      pix[k] = (unsigned int)(yc * WFv + xc);             // < 23200 < 2^15
      wh[k]  = f2h_bits((inb && valid) ? ww[k] : 0.0f);
    }

    uint4 rec;
    rec.x = pix[0] | (valid ? 0x8000u : 0u) | (pix[1] << 16);
    rec.y = pix[2] | (pix[3] << 16);
    rec.z = (unsigned int)wh[0] | ((unsigned int)wh[1] << 16);
    rec.w = (unsigned int)wh[2] | ((unsigned int)wh[3] << 16);
    pdl[slot * NV + v] = rec;
  }
  __syncthreads();
  if (t < 64) { const float c = invl[t]; invl[t] = (c > 0.0f) ? 1.0f / c : 0.0f; }
  __syncthreads();

  // ---- Phase B: taps ----
  const int pg = lane >> 3;    // point within group of 8
  const int ch = lane & 7;     // uint4 chunk (8 channels)

#pragma unroll
  for (int it = 0; it < 2; ++it) {
    const int sl = wave * 16 + it * 8 + pg;
    float acc[8];
#pragma unroll
    for (int j2 = 0; j2 < 8; ++j2) acc[j2] = 0.0f;

#pragma unroll
    for (int v = 0; v < NV; ++v) {
      const uint4 rec = pdl[sl * NV + v];
      if (rec.x & 0x8000u) {
        const unsigned int p00 = rec.x & 0x7fffu;
        const unsigned int p10 = rec.x >> 16;
        const unsigned int p01 = rec.y & 0xffffu;
        const unsigned int p11 = rec.y >> 16;
        const float w0 = h_bits2f((unsigned short)(rec.z & 0xffffu));
        const float w1 = h_bits2f((unsigned short)(rec.z >> 16));
        const float w2 = h_bits2f((unsigned short)(rec.w & 0xffffu));
        const float w3 = h_bits2f((unsigned short)(rec.w >> 16));

        const uint4* fb = feat4 + (size_t)v * PLANE * 8 + ch;
        const uint4 q0 = fb[(size_t)p00 * 8];
        const uint4 q1 = fb[(size_t)p10 * 8];
        const uint4 q2 = fb[(size_t)p01 * 8];
        const uint4 q3 = fb[(size_t)p11 * 8];

        acc[0] = fmaf(w0, bf_lo(q0.x), acc[0]); acc[1] = fmaf(w0, bf_hi(q0.x), acc[1]);
        acc[2] = fmaf(w0, bf_lo(q0.y), acc[2]); acc[3] = fmaf(w0, bf_hi(q0.y), acc[3]);
        acc[4] = fmaf(w0, bf_lo(q0.z), acc[4]); acc[5] = fmaf(w0, bf_hi(q0.z), acc[5]);
        acc[6] = fmaf(w0, bf_lo(q0.w), acc[6]); acc[7] = fmaf(w0, bf_hi(q0.w), acc[7]);

        acc[0] = fmaf(w1, bf_lo(q1.x), acc[0]); acc[1] = fmaf(w1, bf_hi(q1.x), acc[1]);
        acc[2] = fmaf(w1, bf_lo(q1.y), acc[2]); acc[3] = fmaf(w1, bf_hi(q1.y), acc[3]);
        acc[4] = fmaf(w1, bf_lo(q1.z), acc[4]); acc[5] = fmaf(w1, bf_hi(q1.z), acc[5]);
        acc[6] = fmaf(w1, bf_lo(q1.w), acc[6]); acc[7] = fmaf(w1, bf_hi(q1.w), acc[7]);

        acc[0] = fmaf(w2, bf_lo(q2.x), acc[0]); acc[1] = fmaf(w2, bf_hi(q2.x), acc[1]);
        acc[2] = fmaf(w2, bf_lo(q2.y), acc[2]); acc[3] = fmaf(w2, bf_hi(q2.y), acc[3]);
        acc[4] = fmaf(w2, bf_lo(q2.z), acc[4]); acc[5] = fmaf(w2, bf_hi(q2.z), acc[5]);
        acc[6] = fmaf(w2, bf_lo(q2.w), acc[6]); acc[7] = fmaf(w2, bf_hi(q2.w), acc[7]);

        acc[0] = fmaf(w3, bf_lo(q3.x), acc[0]); acc[1] = fmaf(w3, bf_hi(q3.x), acc[1]);
        acc[2] = fmaf(w3, bf_lo(q3.y), acc[2]); acc[3] = fmaf(w3, bf_hi(q3.y), acc[3]);
        acc[4] = fmaf(w3, bf_lo(q3.z), acc[4]); acc[5] = fmaf(w3, bf_hi(q3.z), acc[5]);
        acc[6] = fmaf(w3, bf_lo(q3.w), acc[6]); acc[7] = fmaf(w3, bf_hi(q3.w), acc[7]);
      }
    }

    const float inv = invl[sl];
#pragma unroll
    for (int j2 = 0; j2 < 8; ++j2) tile[sl][ch * 8 + j2] = acc[j2] * inv;
  }

  __syncthreads();

  // ---- Phase C: coalesced store ----
  const size_t obase = (size_t)ix * (NYv * NZv) + (size_t)iy0g * NZv + lane;
#pragma unroll
  for (int i = 0; i < 16; ++i) {
    const int c = i * 4 + wave;
    out[(size_t)c * NVOX + obase] = tile[lane][c];
  }
}

// ---------------------------------------------------------------------------
// Fallback: direct channel-major sampling (no workspace).
// ---------------------------------------------------------------------------
__global__ __launch_bounds__(256) void sample_fallback(
    const float* __restrict__ feat,
    const float* __restrict__ points,
    const float* __restrict__ proj,
    float* __restrict__ out) {
  const int wave = threadIdx.x >> 6;
  const int lane = threadIdx.x & 63;
  const int n = blockIdx.x * 4 + wave;

  const float x = points[n * 3 + 0];
  const float y = points[n * 3 + 1];
  const float z = points[n * 3 + 2];

  float acc = 0.0f;
  int cnt = 0;

#pragma unroll
  for (int v = 0; v < NV; ++v) {
    const float* M = proj + v * 16;
    const float cx = M[0] * x + M[1] * y + M[2]  * z + M[3];
    const float cy = M[4] * x + M[5] * y + M[6]  * z + M[7];
    const float cz = M[8] * x + M[9] * y + M[10] * z + M[11];
    const float dz = (fabsf(cz) > 1e-6f) ? cz : 1e-6f;
    const float u  = cx / dz;
    const float vv = cy / dz;
    const bool valid = (cz > 0.0f) && (u > 0.0f) && (u < 1600.0f) &&
                       (vv > 0.0f) && (vv < 928.0f);
    if (!valid) continue;
    cnt++;
    const float px = u  / 1600.0f * 200.0f - 0.5f;
    const float py = vv / 928.0f  * 116.0f - 0.5f;
    const float fx0 = floorf(px);
    const float fy0 = floorf(py);
    const float wx1 = px - fx0;
    const float wy1 = py - fy0;
    const float wx0 = 1.0f - wx1;
    const float wy0 = 1.0f - wy1;
    const int ix0 = (int)fx0;
    const int iy0 = (int)fy0;
    const float w00 = wx0 * wy0, w10 = wx1 * wy0, w01 = wx0 * wy1, w11 = wx1 * wy1;
    const float* basev = feat + ((size_t)v * NC + lane) * PLANE;
    auto tap = [&](int xi, int yi, float w) {
      if (xi >= 0 && xi < WFv && yi >= 0 && yi < HFv)
        acc += w * basev[yi * WFv + xi];
    };
    tap(ix0,     iy0,     w00);
    tap(ix0 + 1, iy0,     w10);
    tap(ix0,     iy0 + 1, w01);
    tap(ix0 + 1, iy0 + 1, w11);
  }

  const float scale = (cnt > 0) ? (1.0f / (float)cnt) : 0.0f;
  const int iz  = n >> 14;
  const int rem = n & 16383;
  const int iy  = rem >> 7;
  const int ixx = rem & 127;
  out[(((size_t)lane * NXv + ixx) * NYv + iy) * NZv + iz] = acc * scale;
}

extern "C" void kernel_launch(void* const* d_in, const int* in_sizes, int n_in,
                              void* d_out, int out_size, void* d_ws, size_t ws_size,
                              hipStream_t stream) {
  const float* x_fov  = (const float*)d_in[0];  // [1,6,64,116,200] f32
  const float* points = (const float*)d_in[1];  // [131072,3] f32
  const float* proj   = (const float*)d_in[2];  // [6,4,4] f32
  float* out = (float*)d_out;                   // [1,64,128,128,8] f32

  if (ws_size >= FT_BYTES) {
    unsigned int* ft = (unsigned int*)d_ws;
    dim3 tgrid((PLANE + 63) / 64, NV);
    transpose_feat_bf16<<<tgrid, 256, 0, stream>>>(x_fov, ft);
    gather_fused<<<NXv * NYv / 8, 256, 0, stream>>>((const uint4*)ft, points, proj, out);
  } else {
    sample_fallback<<<NVOX / 4, 256, 0, stream>>>(x_fov, points, proj, out);
  }
}

// Round 6
// 99.870 us; speedup vs baseline: 2.3382x; 1.0955x over previous
//
#include <hip/hip_runtime.h>
#include <hip/hip_bf16.h>
#include <hip/hip_fp16.h>

// Problem constants
#define NXv 128
#define NYv 128
#define NZv 8
#define NVOX (NXv * NYv * NZv)   // 131072
#define NV 6
#define NC 64
#define HFv 116
#define WFv 200
#define PLANE (HFv * WFv)        // 23200

#define FT_BYTES ((size_t)NV * PLANE * NC * 2)   // 17,817,600 (bf16 channels-last)

// ---- helpers ---------------------------------------------------------------
__device__ inline unsigned int f2bf(float f) {   // f32 -> bf16 bits, RNE
  unsigned int x = __float_as_uint(f);
  unsigned int r = x + 0x7fffu + ((x >> 16) & 1u);
  return (r >> 16) & 0xffffu;
}
__device__ inline float bf_lo(unsigned int q) { return __uint_as_float(q << 16); }
__device__ inline float bf_hi(unsigned int q) { return __uint_as_float(q & 0xffff0000u); }

__device__ inline unsigned short f2h_bits(float f) {
  __half h = __float2half(f);
  return *reinterpret_cast<unsigned short*>(&h);
}
__device__ inline float h_bits2f(unsigned short u) {
  __half_raw r; r.x = u;
  __half h = *reinterpret_cast<__half*>(&r);
  return __half2float(h);
}

// ---------------------------------------------------------------------------
// K1: Transpose+convert [V][C][PLANE] f32 -> [V][PLANE][C] bf16 (packed).
// ---------------------------------------------------------------------------
__global__ __launch_bounds__(256) void transpose_feat_bf16(
    const float* __restrict__ in, unsigned int* __restrict__ out32) {
  __shared__ float tile[64][65];                 // [pixel][channel]
  const int v  = blockIdx.y;
  const int p0 = blockIdx.x * 64;
  const float* src = in + (size_t)v * NC * PLANE;
  unsigned int* dst = out32 + (size_t)v * PLANE * (NC / 2);
  const int t = threadIdx.x;

#pragma unroll
  for (int i = 0; i < 4; ++i) {
    const int idx = i * 256 + t;
    const int c  = idx >> 4;
    const int p4 = idx & 15;
    const int pp = p0 + p4 * 4;
    if (pp < PLANE) {                            // PLANE%4==0 -> full float4 ok
      const float4 f = *(const float4*)(src + (size_t)c * PLANE + pp);
      tile[p4 * 4 + 0][c] = f.x;
      tile[p4 * 4 + 1][c] = f.y;
      tile[p4 * 4 + 2][c] = f.z;
      tile[p4 * 4 + 3][c] = f.w;
    }
  }
  __syncthreads();

#pragma unroll
  for (int i = 0; i < 2; ++i) {
    const int idx = i * 256 + t;
    const int p   = idx >> 3;
    const int c8  = idx & 7;
    const int pp  = p0 + p;
    if (pp < PLANE) {
      uint4 w;
      w.x = f2bf(tile[p][c8 * 8 + 0]) | (f2bf(tile[p][c8 * 8 + 1]) << 16);
      w.y = f2bf(tile[p][c8 * 8 + 2]) | (f2bf(tile[p][c8 * 8 + 3]) << 16);
      w.z = f2bf(tile[p][c8 * 8 + 4]) | (f2bf(tile[p][c8 * 8 + 5]) << 16);
      w.w = f2bf(tile[p][c8 * 8 + 6]) | (f2bf(tile[p][c8 * 8 + 7]) << 16);
      *(uint4*)(dst + (size_t)pp * 32 + c8 * 4) = w;
    }
  }
}

// ---------------------------------------------------------------------------
// K2: Fused projection + gather + coalesced store (compacted views).
// rec layout (per valid (slot,view)):
//   rec.x = p00 | (v&1)<<15 | p10<<16 | ((v>>1)&1)<<31
//   rec.y = p01 | ((v>>2)&1)<<15 | p11<<16
//   rec.z = f16(w00) | f16(w10)<<16
//   rec.w = f16(w01) | f16(w11)<<16
// Each p* is an INDEPENDENTLY clamped pixel index (< 23200 < 2^15) — matches
// the reference's per-tap clip exactly (round-5 bug: derived +1 taps broke at
// ix0 == -1 and ix0 == WFv-1).
// ---------------------------------------------------------------------------
__global__ __launch_bounds__(256, 8) void gather_fused(
    const uint4* __restrict__ feat4,    // [V*PLANE][8] uint4 (64 bf16 ch)
    const float* __restrict__ points,
    const float* __restrict__ proj,
    float* __restrict__ out) {
  __shared__ unsigned short tile_h[64][66];   // f16 staging, 8.4KB
  __shared__ uint4 pdl[64 * NV];              // 6KB
  __shared__ int   cntl[64];
  __shared__ float invl[64];
  __shared__ float projl[96];

  // spatial swizzle: XCD (~bi&7) owns two 32ix x 32iy squares
  const int bi   = blockIdx.x;
  const int xcd  = bi & 7;
  const int r    = bi >> 3;
  const int tid  = xcd * 2 + (r >> 7);
  const int q    = r & 127;
  const int ix   = (tid & 3) * 32 + (q & 31);
  const int iyg  = (tid >> 2) * 4 + (q >> 5);
  const int iy0g = iyg * 8;

  const int t    = threadIdx.x;
  const int lane = t & 63;
  const int wave = t >> 6;

  if (t < 96) projl[t] = proj[t];
  if (t < 64) cntl[t] = 0;
  __syncthreads();

  // ---- Phase A: projections, compacted per slot ----
  for (int task = t; task < 64 * NV; task += 256) {
    const int slot = task / NV;
    const int v    = task - slot * NV;
    const int j    = slot >> 3;
    const int iz   = slot & 7;
    const int n    = iz * (NXv * NYv) + (iy0g + j) * NXv + ix;

    const float x = points[n * 3 + 0];
    const float y = points[n * 3 + 1];
    const float z = points[n * 3 + 2];

    const float* M = projl + v * 16;
    const float cx = M[0] * x + M[1] * y + M[2]  * z + M[3];
    const float cy = M[4] * x + M[5] * y + M[6]  * z + M[7];
    const float cz = M[8] * x + M[9] * y + M[10] * z + M[11];

    const float dz = (fabsf(cz) > 1e-6f) ? cz : 1e-6f;
    const float u  = cx / dz;
    const float vv = cy / dz;

    const bool valid = (cz > 0.0f) && (u > 0.0f) && (u < 1600.0f) &&
                       (vv > 0.0f) && (vv < 928.0f);
    if (valid) {
      const float px = u  / 1600.0f * 200.0f - 0.5f;
      const float py = vv / 928.0f  * 116.0f - 0.5f;
      const float fx0 = floorf(px);
      const float fy0 = floorf(py);
      const float wx1 = px - fx0;
      const float wy1 = py - fy0;
      const float wx0 = 1.0f - wx1;
      const float wy0 = 1.0f - wy1;
      const int ix0 = (int)fx0;
      const int iy0 = (int)fy0;

      // per-tap in-bounds masks (reference semantics)
      const bool bx0 = (ix0 >= 0) && (ix0 < WFv);
      const bool bx1 = (ix0 + 1 >= 0) && (ix0 + 1 < WFv);
      const bool by0 = (iy0 >= 0) && (iy0 < HFv);
      const bool by1 = (iy0 + 1 >= 0) && (iy0 + 1 < HFv);

      // per-tap independently clamped coords (reference semantics)
      const int xc0 = min(max(ix0, 0), WFv - 1);
      const int xc1 = min(max(ix0 + 1, 0), WFv - 1);
      const int yc0 = min(max(iy0, 0), HFv - 1);
      const int yc1 = min(max(iy0 + 1, 0), HFv - 1);
      const unsigned int p00 = (unsigned int)(yc0 * WFv + xc0);
      const unsigned int p10 = (unsigned int)(yc0 * WFv + xc1);
      const unsigned int p01 = (unsigned int)(yc1 * WFv + xc0);
      const unsigned int p11 = (unsigned int)(yc1 * WFv + xc1);
      const unsigned int uv = (unsigned int)v;

      uint4 rec;
      rec.x = p00 | ((uv & 1u) << 15) | (p10 << 16) | (((uv >> 1) & 1u) << 31);
      rec.y = p01 | (((uv >> 2) & 1u) << 15) | (p11 << 16);
      rec.z = (unsigned int)f2h_bits((bx0 && by0) ? wx0 * wy0 : 0.0f) |
              ((unsigned int)f2h_bits((bx1 && by0) ? wx1 * wy0 : 0.0f) << 16);
      rec.w = (unsigned int)f2h_bits((bx0 && by1) ? wx0 * wy1 : 0.0f) |
              ((unsigned int)f2h_bits((bx1 && by1) ? wx1 * wy1 : 0.0f) << 16);
      const int idx = atomicAdd(&cntl[slot], 1);
      pdl[slot * NV + idx] = rec;
    }
  }
  __syncthreads();
  if (t < 64) { const int c = cntl[t]; invl[t] = (c > 0) ? 1.0f / (float)c : 0.0f; }
  __syncthreads();

  // ---- Phase B: taps over compacted valid views ----
  const int pg = lane >> 3;    // point within group of 8
  const int ch = lane & 7;     // uint4 chunk (8 channels)

#pragma unroll
  for (int it = 0; it < 2; ++it) {
    const int sl = wave * 16 + it * 8 + pg;
    const int mycnt = cntl[sl];
    int km = mycnt;
    km = max(km, __shfl_xor(km, 8));
    km = max(km, __shfl_xor(km, 16));
    km = max(km, __shfl_xor(km, 32));   // wave-uniform max over the 8 points

    float acc[8];
#pragma unroll
    for (int j2 = 0; j2 < 8; ++j2) acc[j2] = 0.0f;

    for (int k = 0; k < km; ++k) {
      if (k < mycnt) {
        const uint4 rec = pdl[sl * NV + k];
        const unsigned int p00 = rec.x & 0x7fffu;
        const unsigned int p10 = (rec.x >> 16) & 0x7fffu;
        const unsigned int p01 = rec.y & 0x7fffu;
        const unsigned int p11 = (rec.y >> 16) & 0x7fffu;
        const unsigned int v = ((rec.x >> 15) & 1u) | (((rec.x >> 31) & 1u) << 1) |
                               (((rec.y >> 15) & 1u) << 2);
        const float w0 = h_bits2f((unsigned short)(rec.z & 0xffffu));
        const float w1 = h_bits2f((unsigned short)(rec.z >> 16));
        const float w2 = h_bits2f((unsigned short)(rec.w & 0xffffu));
        const float w3 = h_bits2f((unsigned short)(rec.w >> 16));

        const uint4* fb = feat4 + (size_t)v * PLANE * 8 + ch;
        const uint4 q0 = fb[(size_t)p00 * 8];
        const uint4 q1 = fb[(size_t)p10 * 8];
        const uint4 q2 = fb[(size_t)p01 * 8];
        const uint4 q3 = fb[(size_t)p11 * 8];

        acc[0] = fmaf(w0, bf_lo(q0.x), acc[0]); acc[1] = fmaf(w0, bf_hi(q0.x), acc[1]);
        acc[2] = fmaf(w0, bf_lo(q0.y), acc[2]); acc[3] = fmaf(w0, bf_hi(q0.y), acc[3]);
        acc[4] = fmaf(w0, bf_lo(q0.z), acc[4]); acc[5] = fmaf(w0, bf_hi(q0.z), acc[5]);
        acc[6] = fmaf(w0, bf_lo(q0.w), acc[6]); acc[7] = fmaf(w0, bf_hi(q0.w), acc[7]);

        acc[0] = fmaf(w1, bf_lo(q1.x), acc[0]); acc[1] = fmaf(w1, bf_hi(q1.x), acc[1]);
        acc[2] = fmaf(w1, bf_lo(q1.y), acc[2]); acc[3] = fmaf(w1, bf_hi(q1.y), acc[3]);
        acc[4] = fmaf(w1, bf_lo(q1.z), acc[4]); acc[5] = fmaf(w1, bf_hi(q1.z), acc[5]);
        acc[6] = fmaf(w1, bf_lo(q1.w), acc[6]); acc[7] = fmaf(w1, bf_hi(q1.w), acc[7]);

        acc[0] = fmaf(w2, bf_lo(q2.x), acc[0]); acc[1] = fmaf(w2, bf_hi(q2.x), acc[1]);
        acc[2] = fmaf(w2, bf_lo(q2.y), acc[2]); acc[3] = fmaf(w2, bf_hi(q2.y), acc[3]);
        acc[4] = fmaf(w2, bf_lo(q2.z), acc[4]); acc[5] = fmaf(w2, bf_hi(q2.z), acc[5]);
        acc[6] = fmaf(w2, bf_lo(q2.w), acc[6]); acc[7] = fmaf(w2, bf_hi(q2.w), acc[7]);

        acc[0] = fmaf(w3, bf_lo(q3.x), acc[0]); acc[1] = fmaf(w3, bf_hi(q3.x), acc[1]);
        acc[2] = fmaf(w3, bf_lo(q3.y), acc[2]); acc[3] = fmaf(w3, bf_hi(q3.y), acc[3]);
        acc[4] = fmaf(w3, bf_lo(q3.z), acc[4]); acc[5] = fmaf(w3, bf_hi(q3.z), acc[5]);
        acc[6] = fmaf(w3, bf_lo(q3.w), acc[6]); acc[7] = fmaf(w3, bf_hi(q3.w), acc[7]);
      }
    }

    const float inv = invl[sl];
#pragma unroll
    for (int j2 = 0; j2 < 4; ++j2) {
      const unsigned int pk =
          (unsigned int)f2h_bits(acc[j2 * 2 + 0] * inv) |
          ((unsigned int)f2h_bits(acc[j2 * 2 + 1] * inv) << 16);
      *(unsigned int*)&tile_h[sl][ch * 8 + j2 * 2] = pk;
    }
  }

  __syncthreads();

  // ---- Phase C: nontemporal coalesced store ----
  const size_t obase = (size_t)ix * (NYv * NZv) + (size_t)iy0g * NZv + lane;
#pragma unroll
  for (int i = 0; i < 16; ++i) {
    const int c = i * 4 + wave;
    const float val = h_bits2f(tile_h[lane][c]);
    __builtin_nontemporal_store(val, &out[(size_t)c * NVOX + obase]);
  }
}

// ---------------------------------------------------------------------------
// Fallback: direct channel-major sampling (no workspace).
// ---------------------------------------------------------------------------
__global__ __launch_bounds__(256) void sample_fallback(
    const float* __restrict__ feat,
    const float* __restrict__ points,
    const float* __restrict__ proj,
    float* __restrict__ out) {
  const int wave = threadIdx.x >> 6;
  const int lane = threadIdx.x & 63;
  const int n = blockIdx.x * 4 + wave;

  const float x = points[n * 3 + 0];
  const float y = points[n * 3 + 1];
  const float z = points[n * 3 + 2];

  float acc = 0.0f;
  int cnt = 0;

#pragma unroll
  for (int v = 0; v < NV; ++v) {
    const float* M = proj + v * 16;
    const float cx = M[0] * x + M[1] * y + M[2]  * z + M[3];
    const float cy = M[4] * x + M[5] * y + M[6]  * z + M[7];
    const float cz = M[8] * x + M[9] * y + M[10] * z + M[11];
    const float dz = (fabsf(cz) > 1e-6f) ? cz : 1e-6f;
    const float u  = cx / dz;
    const float vv = cy / dz;
    const bool valid = (cz > 0.0f) && (u > 0.0f) && (u < 1600.0f) &&
                       (vv > 0.0f) && (vv < 928.0f);
    if (!valid) continue;
    cnt++;
    const float px = u  / 1600.0f * 200.0f - 0.5f;
    const float py = vv / 928.0f  * 116.0f - 0.5f;
    const float fx0 = floorf(px);
    const float fy0 = floorf(py);
    const float wx1 = px - fx0;
    const float wy1 = py - fy0;
    const float wx0 = 1.0f - wx1;
    const float wy0 = 1.0f - wy1;
    const int ix0 = (int)fx0;
    const int iy0 = (int)fy0;
    const float w00 = wx0 * wy0, w10 = wx1 * wy0, w01 = wx0 * wy1, w11 = wx1 * wy1;
    const float* basev = feat + ((size_t)v * NC + lane) * PLANE;
    auto tap = [&](int xi, int yi, float w) {
      if (xi >= 0 && xi < WFv && yi >= 0 && yi < HFv)
        acc += w * basev[yi * WFv + xi];
    };
    tap(ix0,     iy0,     w00);
    tap(ix0 + 1, iy0,     w10);
    tap(ix0,     iy0 + 1, w01);
    tap(ix0 + 1, iy0 + 1, w11);
  }

  const float scale = (cnt > 0) ? (1.0f / (float)cnt) : 0.0f;
  const int iz  = n >> 14;
  const int rem = n & 16383;
  const int iy  = rem >> 7;
  const int ixx = rem & 127;
  out[(((size_t)lane * NXv + ixx) * NYv + iy) * NZv + iz] = acc * scale;
}

extern "C" void kernel_launch(void* const* d_in, const int* in_sizes, int n_in,
                              void* d_out, int out_size, void* d_ws, size_t ws_size,
                              hipStream_t stream) {
  const float* x_fov  = (const float*)d_in[0];  // [1,6,64,116,200] f32
  const float* points = (const float*)d_in[1];  // [131072,3] f32
  const float* proj   = (const float*)d_in[2];  // [6,4,4] f32
  float* out = (float*)d_out;                   // [1,64,128,128,8] f32

  if (ws_size >= FT_BYTES) {
    unsigned int* ft = (unsigned int*)d_ws;
    dim3 tgrid((PLANE + 63) / 64, NV);
    transpose_feat_bf16<<<tgrid, 256, 0, stream>>>(x_fov, ft);
    gather_fused<<<NXv * NYv / 8, 256, 0, stream>>>((const uint4*)ft, points, proj, out);
  } else {
    sample_fallback<<<NVOX / 4, 256, 0, stream>>>(x_fov, points, proj, out);
  }
}